// Round 6
// baseline (216.329 us; speedup 1.0000x reference)
//
#include <hip/hip_runtime.h>
#include <cstdint>
#include <cstddef>

#define B_   256
#define D_   2048
#define U_   2048
#define NTOT 8192    // 4*U
#define BN   32
#define BK   64
#define KC   2048    // K per ksplit (ksplit=2 over K=4096)
#define ITERS (KC / BK)   // 32

typedef _Float16 half8 __attribute__((ext_vector_type(8)));
typedef float floatx16 __attribute__((ext_vector_type(16)));

// ---------------------------------------------------------------------------
// prep: [x|h] fp32 -> f16, chunk-major layout [chunk=k/8][row][8] so the GEMM
// stages A with contiguous global_load_lds and reads fragments as ds_read_b128.
// ---------------------------------------------------------------------------
__global__ __launch_bounds__(256) void prep_kernel(
    const float* __restrict__ x, const float* __restrict__ h,
    _Float16* __restrict__ Ahi)
{
    int gid   = blockIdx.x * 256 + threadIdx.x;   // 131072 total
    int chunk = gid >> 8;                         // 0..511
    int row   = gid & 255;                        // 0..255
    int col0  = chunk * 8;
    const float* src = (col0 < D_) ? (x + row * D_ + col0)
                                   : (h + row * U_ + (col0 - D_));
    float4 v0 = *(const float4*)(src);
    float4 v1 = *(const float4*)(src + 4);
    float v[8] = {v0.x, v0.y, v0.z, v0.w, v1.x, v1.y, v1.z, v1.w};
    half8 hi;
#pragma unroll
    for (int i = 0; i < 8; ++i) hi[i] = (_Float16)v[i];
    *(half8*)(Ahi + (chunk * 256 + row) * 8) = hi;
}

// ---------------------------------------------------------------------------
// GEMM v7: decouple A from the barrier.
// 256 threads (4 waves), wave-tile 64x32 (waves stack M), grid (256,2).
// A: WAVE-PRIVATE LDS slabs — wave w stages only its own 64 rows via
//    global_load_lds (8 x 16B, lane-contiguous), double-buffered.  No other
//    wave touches the slab, so A needs NO barrier: completion is enforced
//    per-wave by a counted vmcnt waiting on the A issued ONE FULL STEP
//    earlier (~a whole step of DMA lead, vs ~0 in v6).
// B: reg-staged fp32 -> f16 -> LDS (2 x 4KB dbuf), 2-step prefetch lead,
//    conflict-free k-rotation layout (rot by (col>>2)*8 halves within the
//    128B row) on BOTH write and read sides.
// Barrier protects only B: pre-barrier wait is lgkmcnt(0) on one ds_write.
// vmcnt floor in the main loop = 16; never drains to 0.
// Step invariant (outstanding vmem at step start): [A(t)=8, B(t+1)=8].
// ---------------------------------------------------------------------------
__global__ __launch_bounds__(256, 2) void gemm_kernel(
    const _Float16* __restrict__ Ahi,
    const float* __restrict__ Wz, const float* __restrict__ Wi,
    const float* __restrict__ Wf, const float* __restrict__ Wo,
    const float* __restrict__ Uz, const float* __restrict__ Ui,
    const float* __restrict__ Uf, const float* __restrict__ Uo,
    float* __restrict__ P)
{
    // A: [buf][wave][chunk c=0..7][row 0..63][8 halfs] = 2 x 32 KB
    __shared__ __align__(16) _Float16 sA[2][4 * 8 * 64 * 8];
    // B: [buf][col 0..31][64 k, rotated] f16 = 2 x 4 KB
    __shared__ __align__(16) _Float16 sB[2][BK * BN];

    const int t    = threadIdx.x;
    const int w    = t >> 6;          // wave 0..3 -> rows w*64..w*64+63
    const int lane = t & 63;
    const int lg   = lane >> 5;
    const int lm   = lane & 31;

    const int nblk = blockIdx.x;      // 0..255
    const int ks   = blockIdx.y;      // 0..1
    const int n0   = nblk * BN;
    const int g    = n0 >> 11;        // gate 0..3
    const int c0   = n0 & (U_ - 1);

    const float* wsel[8] = {Wz, Wi, Wf, Wo, Uz, Ui, Uf, Uo};
    const float* Bm = wsel[ks * 4 + g];        // ks=0 -> W*, ks=1 -> U*
    const int chunk0 = ks * 256;               // A chunk base (chunk = k/8)

    // --- A staging: wave-private.  instr c: lane l -> global row w*64+l,
    //     chunk chunk0 + tt*8 + c; 64 lanes x 16B contiguous.
    const _Float16* Ag = Ahi + (size_t)chunk0 * 2048
                             + (size_t)w * 512 + (size_t)lane * 8;

    // --- B staging: thread covers col = t&31, k rows sk0..sk0+7
    //     (8 coalesced fp32 loads), cvt, one rotated ds_write_b128.
    const int scol = t & 31;
    const int sk0  = (t >> 5) * 8;    // 0,8,...,56
    const float* Bg = Bm + (size_t)sk0 * U_ + c0 + scol;
    // rotation: k stored at row-byte (k*2 + (col>>2)*16) % 128
    const int swb = scol * 128 + ((sk0 * 2 + ((scol >> 2) << 4)) & 127);

    floatx16 acc0 = {}, acc1 = {};
    float rbA[8], rbB[8];

#define ISSUE_A(tt, buf)                                                      \
    {                                                                         \
        _Pragma("unroll")                                                     \
        for (int c = 0; c < 8; ++c)                                           \
            __builtin_amdgcn_global_load_lds(                                 \
                (const __attribute__((address_space(1))) void*)(              \
                    Ag + (size_t)(tt) * 16384 + c * 2048),                    \
                (__attribute__((address_space(3))) void*)(                    \
                    &sA[buf][w * 4096 + c * 512 + lane * 8]),                 \
                16, 0, 0);                                                    \
    }

#define ISSUE_B(tt, rb)                                                       \
    {                                                                         \
        _Pragma("unroll")                                                     \
        for (int j = 0; j < 8; ++j)                                           \
            rb[j] = Bg[((size_t)(tt) * 64 + j) * U_];                         \
    }

#define WRITE_B(rb, buf)                                                      \
    {                                                                         \
        half8 hv;                                                             \
        _Pragma("unroll")                                                     \
        for (int j = 0; j < 8; ++j) hv[j] = (_Float16)rb[j];                  \
        *(half8*)((char*)&sB[buf][0] + swb) = hv;                             \
    }

#define COMPUTE(cur)                                                          \
    {                                                                         \
        const _Float16* wA = &sA[cur][w * 4096];                              \
        const char*     bB = (const char*)&sB[cur][0];                        \
        half8 af0[4], af1[4], bfr[4];                                         \
        _Pragma("unroll")                                                     \
        for (int kin = 0; kin < 4; ++kin) {                                   \
            af0[kin] = *(const half8*)(wA + (kin * 2 + lg) * 512 + lm * 8);   \
            af1[kin] = *(const half8*)(wA + (kin * 2 + lg) * 512 + lm * 8 + 256); \
            bfr[kin] = *(const half8*)(bB + lm * 128 +                        \
                ((kin * 32 + lg * 16 + ((lm >> 2) << 4)) & 127));             \
        }                                                                     \
        __builtin_amdgcn_s_setprio(1);                                        \
        _Pragma("unroll")                                                     \
        for (int kin = 0; kin < 4; ++kin) {                                   \
            acc0 = __builtin_amdgcn_mfma_f32_32x32x16_f16(af0[kin], bfr[kin], acc0, 0, 0, 0); \
            acc1 = __builtin_amdgcn_mfma_f32_32x32x16_f16(af1[kin], bfr[kin], acc1, 0, 0, 0); \
        }                                                                     \
        __builtin_amdgcn_s_setprio(0);                                        \
    }

    // ---- prologue: A(0)[8] -> B(0)[8] -> B(1)[8]; retire A(0)+B(0);
    //      write B(0); barrier.  Leaves [B(1)]=8 outstanding.
    ISSUE_A(0, 0);
    ISSUE_B(0, rbA);
    ISSUE_B(1, rbB);
    asm volatile("s_waitcnt vmcnt(8)" ::: "memory");
    WRITE_B(rbA, 0);
    asm volatile("s_waitcnt lgkmcnt(0)" ::: "memory");
    __builtin_amdgcn_s_barrier();

    // ---- main loop: steps t=tt (even) / t=tt+1 (odd); tt = 0..28
    for (int tt = 0; tt < ITERS - 2; tt += 2) {
        // even step t: compute sA buf0 / sB[0]
        ISSUE_A(tt + 1, 1);
        ISSUE_B(tt + 2, rbA);
        asm volatile("s_waitcnt vmcnt(24)" ::: "memory");   // A(t) done
        COMPUTE(0);
        asm volatile("s_waitcnt vmcnt(16)" ::: "memory");   // B(t+1) done
        WRITE_B(rbB, 1);
        asm volatile("s_waitcnt lgkmcnt(0)" ::: "memory");
        __builtin_amdgcn_s_barrier();

        // odd step t+1: compute sA buf1 / sB[1]
        ISSUE_A(tt + 2, 0);
        ISSUE_B(tt + 3, rbB);
        asm volatile("s_waitcnt vmcnt(24)" ::: "memory");   // A(t+1) done
        COMPUTE(1);
        asm volatile("s_waitcnt vmcnt(16)" ::: "memory");   // B(t+2) done
        WRITE_B(rbA, 0);
        asm volatile("s_waitcnt lgkmcnt(0)" ::: "memory");
        __builtin_amdgcn_s_barrier();
    }

    // ---- epilogue: t = ITERS-2 (even, buf0/sB0); no B(ITERS) exists
    ISSUE_A(ITERS - 1, 1);
    asm volatile("s_waitcnt vmcnt(16)" ::: "memory");       // A(30) done
    COMPUTE(0);
    asm volatile("s_waitcnt vmcnt(8)" ::: "memory");        // B(31) done
    WRITE_B(rbB, 1);
    asm volatile("s_waitcnt lgkmcnt(0)" ::: "memory");
    __builtin_amdgcn_s_barrier();
    // t = ITERS-1 (odd, buf1/sB1)
    asm volatile("s_waitcnt vmcnt(0)" ::: "memory");        // A(31) done
    COMPUTE(1);

#undef ISSUE_A
#undef ISSUE_B
#undef WRITE_B
#undef COMPUTE

    // C/D layout: col=lane&31, row=(r&3)+8*(r>>2)+4*(lane>>5)
    float* Pks = P + (size_t)ks * ((size_t)B_ * NTOT);
#pragma unroll
    for (int r = 0; r < 16; ++r) {
        int m = w * 64 + 4 * lg + (r & 3) + 8 * (r >> 2);
        Pks[(size_t)m * NTOT + n0 + lm] = acc0[r];
    }
#pragma unroll
    for (int r = 0; r < 16; ++r) {
        int m = w * 64 + 32 + 4 * lg + (r & 3) + 8 * (r >> 2);
        Pks[(size_t)m * NTOT + n0 + lm] = acc1[r];
    }
}

// ---------------------------------------------------------------------------
// gates: reduce 2 partials, add bias, sLSTM exponential-gate math,
// out = stack([h_t, c_t, n_t, m_t])
// ---------------------------------------------------------------------------
__global__ __launch_bounds__(256) void gates_kernel(
    const float* __restrict__ P,
    const float* __restrict__ c_prev, const float* __restrict__ n_prev,
    const float* __restrict__ m_prev,
    const float* __restrict__ bz, const float* __restrict__ bi,
    const float* __restrict__ bf, const float* __restrict__ bo,
    float* __restrict__ out)
{
    const size_t PS = (size_t)B_ * NTOT;
    const int OS = B_ * U_;
    int gid = blockIdx.x * 256 + threadIdx.x;   // 131072
    int m = gid >> 9;
    int u = (gid & 511) * 4;

    float pre[4][4];
#pragma unroll
    for (int gi = 0; gi < 4; ++gi) {
        const float* base = P + (size_t)m * NTOT + gi * U_ + u;
        float4 s0 = *(const float4*)(base);
        float4 s1 = *(const float4*)(base + PS);
        pre[gi][0] = s0.x + s1.x;
        pre[gi][1] = s0.y + s1.y;
        pre[gi][2] = s0.z + s1.z;
        pre[gi][3] = s0.w + s1.w;
    }
    float4 bzv = *(const float4*)(bz + u);
    float4 biv = *(const float4*)(bi + u);
    float4 bfv = *(const float4*)(bf + u);
    float4 bov = *(const float4*)(bo + u);
    float bza[4] = {bzv.x, bzv.y, bzv.z, bzv.w};
    float bia[4] = {biv.x, biv.y, biv.z, biv.w};
    float bfa[4] = {bfv.x, bfv.y, bfv.z, bfv.w};
    float boa[4] = {bov.x, bov.y, bov.z, bov.w};

    float4 cp4 = *(const float4*)(c_prev + m * U_ + u);
    float4 np4 = *(const float4*)(n_prev + m * U_ + u);
    float4 mp4 = *(const float4*)(m_prev + m * U_ + u);
    float cpa[4] = {cp4.x, cp4.y, cp4.z, cp4.w};
    float npa[4] = {np4.x, np4.y, np4.z, np4.w};
    float mpa[4] = {mp4.x, mp4.y, mp4.z, mp4.w};

    float hr[4], cr[4], nr[4], mr[4];
#pragma unroll
    for (int e = 0; e < 4; ++e) {
        float zt = pre[0][e] + bza[e];
        float it = pre[1][e] + bia[e];
        float ft = pre[2][e] + bfa[e];
        float ot = pre[3][e] + boa[e];
        float mp = mpa[e];
        float m_t = fmaxf(it + mp, it);
        float i_t = expf(it - m_t);
        float f_t = expf(ft + mp - m_t);
        float o_t = 1.0f / (1.0f + expf(-ot));
        float z_t = tanhf(zt);
        float c_t = f_t * cpa[e] + i_t * z_t;
        float n_t = f_t * npa[e] + i_t;
        float h_t = o_t * (c_t / (n_t + 1e-8f));
        hr[e] = h_t; cr[e] = c_t; nr[e] = n_t; mr[e] = m_t;
    }
    float4 hv = {hr[0], hr[1], hr[2], hr[3]};
    float4 cv = {cr[0], cr[1], cr[2], cr[3]};
    float4 nv = {nr[0], nr[1], nr[2], nr[3]};
    float4 mv = {mr[0], mr[1], mr[2], mr[3]};
    *(float4*)(out + 0 * OS + m * U_ + u) = hv;
    *(float4*)(out + 1 * OS + m * U_ + u) = cv;
    *(float4*)(out + 2 * OS + m * U_ + u) = nv;
    *(float4*)(out + 3 * OS + m * U_ + u) = mv;
}

extern "C" void kernel_launch(void* const* d_in, const int* in_sizes, int n_in,
                              void* d_out, int out_size, void* d_ws, size_t ws_size,
                              hipStream_t stream)
{
    const float* x  = (const float*)d_in[0];
    const float* h  = (const float*)d_in[1];
    const float* cp = (const float*)d_in[2];
    const float* np = (const float*)d_in[3];
    const float* mp = (const float*)d_in[4];
    const float* Wz = (const float*)d_in[5];
    const float* Wi = (const float*)d_in[6];
    const float* Wf = (const float*)d_in[7];
    const float* Wo = (const float*)d_in[8];
    const float* bz = (const float*)d_in[9];
    const float* bi = (const float*)d_in[10];
    const float* bf = (const float*)d_in[11];
    const float* bo = (const float*)d_in[12];
    const float* Uz = (const float*)d_in[13];
    const float* Ui = (const float*)d_in[14];
    const float* Uf = (const float*)d_in[15];
    const float* Uo = (const float*)d_in[16];

    float* P = (float*)d_ws;                         // 2*256*8192 f32 = 16.8 MB
    _Float16* Ahi = (_Float16*)((char*)d_ws + (size_t)2 * B_ * NTOT * sizeof(float));

    prep_kernel<<<512, 256, 0, stream>>>(x, h, Ahi);
    gemm_kernel<<<dim3(256, 2), 256, 0, stream>>>(Ahi,
        Wz, Wi, Wf, Wo, Uz, Ui, Uf, Uo, P);
    gates_kernel<<<512, 256, 0, stream>>>(P, cp, np, mp, bz, bi, bf, bo,
        (float*)d_out);
}

// Round 7
// 206.182 us; speedup vs baseline: 1.0492x; 1.0492x over previous
//
#include <hip/hip_runtime.h>
#include <cstdint>
#include <cstddef>

#define B_   256
#define D_   2048
#define U_   2048
#define NTOT 8192    // 4*U
#define BM   128
#define BN   128
#define BK   64
#define KSP  4
#define KC   1024    // K per ksplit (ksplit=4 over K=4096)
#define ITERS (KC / BK)   // 16

typedef _Float16 half8 __attribute__((ext_vector_type(8)));
typedef float floatx16 __attribute__((ext_vector_type(16)));

// ---------------------------------------------------------------------------
// prep: [x|h] fp32 -> f16, chunk-major layout [chunk=k/8][row][8] so the GEMM
// stages A with contiguous global_load_lds and reads fragments as ds_read_b128.
// ---------------------------------------------------------------------------
__global__ __launch_bounds__(256) void prep_kernel(
    const float* __restrict__ x, const float* __restrict__ h,
    _Float16* __restrict__ Ahi)
{
    int gid   = blockIdx.x * 256 + threadIdx.x;   // 131072 total
    int chunk = gid >> 8;                         // 0..511
    int row   = gid & 255;                        // 0..255
    int col0  = chunk * 8;
    const float* src = (col0 < D_) ? (x + row * D_ + col0)
                                   : (h + row * U_ + (col0 - D_));
    float4 v0 = *(const float4*)(src);
    float4 v1 = *(const float4*)(src + 4);
    float v[8] = {v0.x, v0.y, v0.z, v0.w, v1.x, v1.y, v1.z, v1.w};
    half8 hi;
#pragma unroll
    for (int i = 0; i < 8; ++i) hi[i] = (_Float16)v[i];
    *(half8*)(Ahi + (chunk * 256 + row) * 8) = hi;
}

// ---------------------------------------------------------------------------
// GEMM v8: m97 geometry.  Tile 128x128, BK=64, 256 threads = 4 waves of
// 64x64 (2x2 of 32x32x16 MFMA) -> 16 MFMA : 16 ds_read_b128 per wave-step
// (2.7x the ratio of all previous rounds).  ksplit=4 -> grid (128,4) = 512
// blocks = 2 blocks/CU (LDS 64 KB/blk, VGPR ~200 -> 8 waves/CU).
// A: f16 chunk-major via global_load_lds, LDS [chunk][row][8] (flat copy).
// B: fp32 scalar loads (per-col, coalesced 256B/instr) -> pk-cvt -> LDS
//    [kslot][col][8]; ALL four LDS access patterns are lane-contiguous
//    1024B => zero bank conflicts by construction (v0's proven property).
// Sync: v4's counted vmcnt (floor 32, never 0 in loop), B 2-step lead,
// A 1-step lead, raw s_barrier.  P written as f16 (4 partials, 16.8 MB).
// XCD swizzle pins m-twin blocks (sharing B panels) to the same XCD.
// ---------------------------------------------------------------------------
__global__ __launch_bounds__(256) void gemm_kernel(
    const _Float16* __restrict__ Ahi,
    const float* __restrict__ Wz, const float* __restrict__ Wi,
    const float* __restrict__ Wf, const float* __restrict__ Wo,
    const float* __restrict__ Uz, const float* __restrict__ Ui,
    const float* __restrict__ Uf, const float* __restrict__ Uo,
    _Float16* __restrict__ P)
{
    __shared__ __align__(16) _Float16 sA[2][8 * 128 * 8];   // 2 x 16 KB
    __shared__ __align__(16) _Float16 sB[2][8 * 128 * 8];   // 2 x 16 KB

    const int t    = threadIdx.x;
    const int w    = t >> 6;
    const int lane = t & 63;
    const int lg   = lane >> 5;
    const int lm   = lane & 31;
    const int wm   = w >> 1;          // 0/1: M half (64 rows)
    const int wn   = w & 1;           // 0/1: N half (64 cols)

    // XCD swizzle: bx -> (mt, nt) with m-twins (same nt) on the same XCD.
    const int bx = blockIdx.x;        // 0..127
    const int mt = (bx >> 3) & 1;
    const int nt = ((bx >> 4) << 3) | (bx & 7);
    const int ks = blockIdx.y;        // 0..3

    const int m0 = mt * BM;
    const int n0 = nt * BN;           // within 8192
    const int g  = n0 >> 11;          // gate 0..3
    const int c0 = n0 & (U_ - 1);

    const float* wsel[8] = {Wz, Wi, Wf, Wo, Uz, Ui, Uf, Uo};
    const float* Bm = wsel[(ks >> 1) * 4 + g];   // ks 0,1 -> W*; 2,3 -> U*
    const int km = (ks & 1) * 1024;              // row base within matrix
    const int chunkbase = ks * 128;              // A chunk base (chunk = k/8)

    // --- A staging (flat copy, 4 x gload_lds/thread):
    //     instr i covers chunk c = 2i + (t>>7), row = t&127.
    const int arow  = t & 127;
    const int ahalf = t >> 7;

    // --- B staging: thread owns col bcol = t&127, k-slots sbase..sbase+3.
    const int bcol  = t & 127;
    const int sbase = (t >> 7) * 4;
    const float* Bg = Bm + (size_t)km * U_ + c0 + bcol;

    floatx16 acc00 = {}, acc01 = {}, acc10 = {}, acc11 = {};
    float rbA[32], rbB[32];

#define ISSUE_A(tt, buf)                                                      \
    {                                                                         \
        _Pragma("unroll")                                                     \
        for (int i = 0; i < 4; ++i) {                                         \
            int c = 2 * i + ahalf;                                            \
            __builtin_amdgcn_global_load_lds(                                 \
                (const __attribute__((address_space(1))) void*)(              \
                    Ahi + (size_t)(chunkbase + (tt) * 8 + c) * 2048           \
                        + (m0 + arow) * 8),                                   \
                (__attribute__((address_space(3))) void*)(                    \
                    &sA[buf][i * 2048 + t * 8]),                              \
                16, 0, 0);                                                    \
        }                                                                     \
    }

#define ISSUE_B(tt, rb)                                                       \
    {                                                                         \
        _Pragma("unroll")                                                     \
        for (int sc = 0; sc < 4; ++sc)                                        \
            _Pragma("unroll")                                                 \
            for (int j = 0; j < 8; ++j)                                       \
                rb[sc * 8 + j] =                                              \
                    Bg[(size_t)((tt) * 64 + (sbase + sc) * 8 + j) * U_];      \
    }

#define WRITE_B(rb, buf)                                                      \
    {                                                                         \
        _Pragma("unroll")                                                     \
        for (int sc = 0; sc < 4; ++sc) {                                      \
            half8 hv;                                                         \
            _Pragma("unroll")                                                 \
            for (int j = 0; j < 8; ++j) hv[j] = (_Float16)rb[sc * 8 + j];     \
            *(half8*)(&sB[buf][(sbase + sc) * 1024 + bcol * 8]) = hv;         \
        }                                                                     \
    }

#define COMPUTE(cur)                                                          \
    {                                                                         \
        __builtin_amdgcn_s_setprio(1);                                        \
        _Pragma("unroll")                                                     \
        for (int kin = 0; kin < 4; ++kin) {                                   \
            int cs = kin * 2 + lg;                                            \
            half8 a0 = *(const half8*)(&sA[cur][cs * 1024 + (wm * 64 + lm) * 8]);       \
            half8 a1 = *(const half8*)(&sA[cur][cs * 1024 + (wm * 64 + 32 + lm) * 8]);  \
            half8 b0 = *(const half8*)(&sB[cur][cs * 1024 + (wn * 64 + lm) * 8]);       \
            half8 b1 = *(const half8*)(&sB[cur][cs * 1024 + (wn * 64 + 32 + lm) * 8]);  \
            acc00 = __builtin_amdgcn_mfma_f32_32x32x16_f16(a0, b0, acc00, 0, 0, 0);     \
            acc01 = __builtin_amdgcn_mfma_f32_32x32x16_f16(a0, b1, acc01, 0, 0, 0);     \
            acc10 = __builtin_amdgcn_mfma_f32_32x32x16_f16(a1, b0, acc10, 0, 0, 0);     \
            acc11 = __builtin_amdgcn_mfma_f32_32x32x16_f16(a1, b1, acc11, 0, 0, 0);     \
        }                                                                     \
        __builtin_amdgcn_s_setprio(0);                                        \
    }

    // ---- prologue: B(0)[32] -> A(0)[4] -> B(1)[32]; cvt B(0) after
    //      vmcnt(36) (retires B(0)); pre-barrier vmcnt(32) (retires A(0),
    //      leaves B(1) in flight).
    ISSUE_B(0, rbA);
    ISSUE_A(0, 0);
    ISSUE_B(1, rbB);
    asm volatile("s_waitcnt vmcnt(36)" ::: "memory");
    WRITE_B(rbA, 0);
    asm volatile("s_waitcnt vmcnt(32) lgkmcnt(0)" ::: "memory");
    __builtin_amdgcn_s_barrier();

    // ---- main loop (2x unrolled; steady top-of-step outstanding = B(t+1)=32)
    for (int tt = 0; tt < ITERS - 2; tt += 2) {
        // even step t=tt: compute buf0; rbB holds B(t+1)
        ISSUE_A(tt + 1, 1);
        ISSUE_B(tt + 2, rbA);
        COMPUTE(0);
        asm volatile("s_waitcnt vmcnt(36)" ::: "memory");   // B(t+1) regs done
        WRITE_B(rbB, 1);
        asm volatile("s_waitcnt vmcnt(32) lgkmcnt(0)" ::: "memory"); // A(t+1)
        __builtin_amdgcn_s_barrier();

        // odd step t=tt+1: compute buf1; rbA holds B(t+1)
        ISSUE_A(tt + 2, 0);
        ISSUE_B(tt + 3, rbB);
        COMPUTE(1);
        asm volatile("s_waitcnt vmcnt(36)" ::: "memory");
        WRITE_B(rbA, 0);
        asm volatile("s_waitcnt vmcnt(32) lgkmcnt(0)" ::: "memory");
        __builtin_amdgcn_s_barrier();
    }

    // ---- epilogue: step ITERS-2 (even, buf0); rbB holds B(ITERS-1)
    ISSUE_A(ITERS - 1, 1);
    COMPUTE(0);
    asm volatile("s_waitcnt vmcnt(4)" ::: "memory");        // B regs done
    WRITE_B(rbB, 1);
    asm volatile("s_waitcnt vmcnt(0) lgkmcnt(0)" ::: "memory");
    __builtin_amdgcn_s_barrier();
    // step ITERS-1 (odd, buf1)
    COMPUTE(1);

#undef ISSUE_A
#undef ISSUE_B
#undef WRITE_B
#undef COMPUTE

    // C/D layout: col=lane&31, row=(r&3)+8*(r>>2)+4*(lane>>5).  P is f16.
    _Float16* Pks = P + (size_t)ks * ((size_t)B_ * NTOT);
    const floatx16* accs[4] = {&acc00, &acc01, &acc10, &acc11};
#pragma unroll
    for (int mi = 0; mi < 2; ++mi)
#pragma unroll
        for (int ni = 0; ni < 2; ++ni) {
            const floatx16& a = *accs[mi * 2 + ni];
            int colg = n0 + wn * 64 + ni * 32 + lm;
#pragma unroll
            for (int r = 0; r < 16; ++r) {
                int m = m0 + wm * 64 + mi * 32 + 4 * lg + (r & 3) + 8 * (r >> 2);
                Pks[(size_t)m * NTOT + colg] = (_Float16)a[r];
            }
        }
}

// ---------------------------------------------------------------------------
// gates: reduce 4 f16 partials, add bias, sLSTM exponential-gate math,
// out = stack([h_t, c_t, n_t, m_t]).  8 outputs per thread.
// ---------------------------------------------------------------------------
__global__ __launch_bounds__(256) void gates_kernel(
    const _Float16* __restrict__ P,
    const float* __restrict__ c_prev, const float* __restrict__ n_prev,
    const float* __restrict__ m_prev,
    const float* __restrict__ bz, const float* __restrict__ bi,
    const float* __restrict__ bf, const float* __restrict__ bo,
    float* __restrict__ out)
{
    const size_t PS = (size_t)B_ * NTOT;
    const int OS = B_ * U_;
    int gid = blockIdx.x * 256 + threadIdx.x;   // 65536
    int m = gid >> 8;
    int u = (gid & 255) * 8;

    float pre[4][8];
#pragma unroll
    for (int gi = 0; gi < 4; ++gi) {
#pragma unroll
        for (int e = 0; e < 8; ++e) pre[gi][e] = 0.0f;
#pragma unroll
        for (int ksp = 0; ksp < 4; ++ksp) {
            half8 v = *(const half8*)(P + (size_t)ksp * PS
                                        + (size_t)m * NTOT + gi * 2048 + u);
#pragma unroll
            for (int e = 0; e < 8; ++e) pre[gi][e] += (float)v[e];
        }
    }

    float bza[8], bia[8], bfa[8], boa[8], cpa[8], npa[8], mpa[8];
    *(float4*)(bza)     = *(const float4*)(bz + u);
    *(float4*)(bza + 4) = *(const float4*)(bz + u + 4);
    *(float4*)(bia)     = *(const float4*)(bi + u);
    *(float4*)(bia + 4) = *(const float4*)(bi + u + 4);
    *(float4*)(bfa)     = *(const float4*)(bf + u);
    *(float4*)(bfa + 4) = *(const float4*)(bf + u + 4);
    *(float4*)(boa)     = *(const float4*)(bo + u);
    *(float4*)(boa + 4) = *(const float4*)(bo + u + 4);
    *(float4*)(cpa)     = *(const float4*)(c_prev + m * U_ + u);
    *(float4*)(cpa + 4) = *(const float4*)(c_prev + m * U_ + u + 4);
    *(float4*)(npa)     = *(const float4*)(n_prev + m * U_ + u);
    *(float4*)(npa + 4) = *(const float4*)(n_prev + m * U_ + u + 4);
    *(float4*)(mpa)     = *(const float4*)(m_prev + m * U_ + u);
    *(float4*)(mpa + 4) = *(const float4*)(m_prev + m * U_ + u + 4);

    float hr[8], cr[8], nr[8], mr[8];
#pragma unroll
    for (int e = 0; e < 8; ++e) {
        float zt = pre[0][e] + bza[e];
        float it = pre[1][e] + bia[e];
        float ft = pre[2][e] + bfa[e];
        float ot = pre[3][e] + boa[e];
        float mp = mpa[e];
        float m_t = fmaxf(it + mp, it);
        float i_t = expf(it - m_t);
        float f_t = expf(ft + mp - m_t);
        float o_t = 1.0f / (1.0f + expf(-ot));
        float z_t = tanhf(zt);
        float c_t = f_t * cpa[e] + i_t * z_t;
        float n_t = f_t * npa[e] + i_t;
        float h_t = o_t * (c_t / (n_t + 1e-8f));
        hr[e] = h_t; cr[e] = c_t; nr[e] = n_t; mr[e] = m_t;
    }
    float* ob = out + m * U_ + u;
    *(float4*)(ob + 0 * OS)     = *(float4*)(hr);
    *(float4*)(ob + 0 * OS + 4) = *(float4*)(hr + 4);
    *(float4*)(ob + 1 * OS)     = *(float4*)(cr);
    *(float4*)(ob + 1 * OS + 4) = *(float4*)(cr + 4);
    *(float4*)(ob + 2 * OS)     = *(float4*)(nr);
    *(float4*)(ob + 2 * OS + 4) = *(float4*)(nr + 4);
    *(float4*)(ob + 3 * OS)     = *(float4*)(mr);
    *(float4*)(ob + 3 * OS + 4) = *(float4*)(mr + 4);
}

extern "C" void kernel_launch(void* const* d_in, const int* in_sizes, int n_in,
                              void* d_out, int out_size, void* d_ws, size_t ws_size,
                              hipStream_t stream)
{
    const float* x  = (const float*)d_in[0];
    const float* h  = (const float*)d_in[1];
    const float* cp = (const float*)d_in[2];
    const float* np = (const float*)d_in[3];
    const float* mp = (const float*)d_in[4];
    const float* Wz = (const float*)d_in[5];
    const float* Wi = (const float*)d_in[6];
    const float* Wf = (const float*)d_in[7];
    const float* Wo = (const float*)d_in[8];
    const float* bz = (const float*)d_in[9];
    const float* bi = (const float*)d_in[10];
    const float* bf = (const float*)d_in[11];
    const float* bo = (const float*)d_in[12];
    const float* Uz = (const float*)d_in[13];
    const float* Ui = (const float*)d_in[14];
    const float* Uf = (const float*)d_in[15];
    const float* Uo = (const float*)d_in[16];

    // workspace: P (f16, 4 partials) = 4*256*8192*2 = 16.8 MB, then Ahi 4 MB
    _Float16* P   = (_Float16*)d_ws;
    _Float16* Ahi = (_Float16*)((char*)d_ws
                     + (size_t)KSP * B_ * NTOT * sizeof(_Float16));

    prep_kernel<<<512, 256, 0, stream>>>(x, h, Ahi);
    gemm_kernel<<<dim3(128, KSP), 256, 0, stream>>>(Ahi,
        Wz, Wi, Wf, Wo, Uz, Ui, Uf, Uo, P);
    gates_kernel<<<256, 256, 0, stream>>>(P, cp, np, mp, bz, bi, bf, bo,
        (float*)d_out);
}